// Round 7
// baseline (162.607 us; speedup 1.0000x reference)
//
#include <hip/hip_runtime.h>
#include <hip/hip_bf16.h>

using f32x4    = __attribute__((ext_vector_type(4))) float;
using bf16x8   = __attribute__((ext_vector_type(8))) __bf16;
using ushort8  = __attribute__((ext_vector_type(8))) unsigned short;
using ushort4v = __attribute__((ext_vector_type(4))) unsigned short;
using float4v  = __attribute__((ext_vector_type(4))) float;

#define LOG2E 1.44269504088896340736f
#define SHIFT_L2 5.77078016355585f   // 4 * log2(e): p = exp(s_true - 4)

static __device__ __forceinline__ unsigned short f2bf(float f) {
  union { __hip_bfloat16 h; unsigned short u; } cv;
  cv.h = __float2bfloat16(f);
  return cv.u;
}
static __device__ __forceinline__ bf16x8 ld_bf8_g(const unsigned short* p) {
  ushort8 u = *(const ushort8*)p;
  return __builtin_bit_cast(bf16x8, u);
}
static __device__ __forceinline__ bf16x8 ld_bf8_l(const char* p) {
  ushort8 u = *(const ushort8*)p;
  return __builtin_bit_cast(bf16x8, u);
}
static __device__ __forceinline__ float fast_exp2(float x) {
#if __has_builtin(__builtin_amdgcn_exp2f)
  return __builtin_amdgcn_exp2f(x);
#else
  return exp2f(x);
#endif
}
static __device__ __forceinline__ void gload16(const void* g, void* l) {
  __builtin_amdgcn_global_load_lds(
      (const __attribute__((address_space(1))) void*)g,
      (__attribute__((address_space(3))) void*)l, 16, 0, 0);
}

// ------------- W prep + zero-init of out accumulator and lacc ---------------
__global__ __launch_bounds__(256) void wprep_kernel(
    const float* __restrict__ wq, const float* __restrict__ wk,
    const float* __restrict__ wv, unsigned short* __restrict__ Wt,
    float* __restrict__ outz, float* __restrict__ lacc) {
  int idx = blockIdx.x * 256 + threadIdx.x;   // 0 .. 196607
  {
    int col = idx >> 10;                      // 0..191
    int k   = idx & 1023;
    const float* w = (col < 64) ? wq : (col < 128) ? wk : wv;
    int c = col & 63;
    Wt[idx] = f2bf(w[k * 64 + c]);
  }
  for (int i = idx; i < 1048576 + 16384; i += 196608) {
    if (i < 1048576) outz[i] = 0.f;
    else lacc[i - 1048576] = 0.f;
  }
}

// -------- QKV projection: BM=32 (512 blocks), BN=192, BK=64 -----------------
// q scaled by 1/8*log2(e), layout [b*4096+s][64].
// k,v written into PRE-SWIZZLED 16 KB panels per (batch, 128-row chunk):
//   K panel byte = (r*128 + c*2)  ^ ((r&7)<<4)   (r = s&127, c = 0..63)
//   V panel byte = (d*256 + sl*2) ^ ((d&7)<<4)   (transposed; sl = s&127)
__global__ __launch_bounds__(256) void proj_kernel(
    const float* __restrict__ x, const unsigned short* __restrict__ Wt,
    const float* __restrict__ bq, const float* __restrict__ bk,
    const float* __restrict__ bv,
    unsigned short* __restrict__ qb, unsigned short* __restrict__ kswz,
    unsigned short* __restrict__ vswz) {
  __shared__ __align__(16) char As[32 * 128];
  __shared__ __align__(16) char Bs[192 * 128];
  int tid = threadIdx.x, wave = tid >> 6, lane = tid & 63;
  int rowBase = blockIdx.x * 32;
  int rhalf = (wave & 1) * 16;
  int chalf = (wave >> 1) * 96;
  int l15 = lane & 15, lh = lane >> 4;

  f32x4 zero4 = {0.f, 0.f, 0.f, 0.f};
  f32x4 acc[6];
#pragma unroll
  for (int i = 0; i < 6; ++i) acc[i] = zero4;

  for (int kt = 0; kt < 16; ++kt) {
    int k0 = kt * 64;
    {
      int row = tid >> 3, c0 = (tid & 7) * 8;
      const float4v* src = (const float4v*)(x + (size_t)(rowBase + row) * 1024 + k0 + c0);
      float4v f0 = src[0], f1 = src[1];
      ushort8 u;
#pragma unroll
      for (int e = 0; e < 4; ++e) { u[e] = f2bf(f0[e]); u[4 + e] = f2bf(f1[e]); }
      *(ushort8*)(As + ((row * 128 + c0 * 2) ^ ((row & 7) << 4))) = u;
    }
#pragma unroll
    for (int i = 0; i < 6; ++i) {
      int c = tid + 256 * i;
      int col = c >> 3, kc = c & 7;
      ushort8 v = *(const ushort8*)(Wt + (size_t)col * 1024 + k0 + kc * 8);
      *(ushort8*)(Bs + ((col * 128 + kc * 16) ^ ((col & 7) << 4))) = v;
    }
    __syncthreads();
    bf16x8 a[2];
#pragma unroll
    for (int ks = 0; ks < 2; ++ks) {
      int row = rhalf + l15;
      a[ks] = ld_bf8_l(As + ((row * 128 + ks * 64 + lh * 16) ^ ((row & 7) << 4)));
    }
#pragma unroll
    for (int cf = 0; cf < 6; ++cf) {
      int col = chalf + cf * 16 + l15;
#pragma unroll
      for (int ks = 0; ks < 2; ++ks) {
        bf16x8 b = ld_bf8_l(Bs + ((col * 128 + ks * 64 + lh * 16) ^ ((col & 7) << 4)));
        acc[cf] = __builtin_amdgcn_mfma_f32_16x16x32_bf16(a[ks], b, acc[cf], 0, 0, 0);
      }
    }
    __syncthreads();
  }
#pragma unroll
  for (int cf = 0; cf < 6; ++cf) {
    int col = chalf + cf * 16 + l15;
    int sel = col >> 6, c64 = col & 63;
    const float* bias = (sel == 0) ? bq : (sel == 1) ? bk : bv;
    float bb = bias[c64];
    if (sel == 0) {
#pragma unroll
      for (int r = 0; r < 4; ++r) {
        int row = rowBase + rhalf + lh * 4 + r;
        qb[(size_t)row * 64 + c64] = f2bf((acc[cf][r] + bb) * (0.125f * LOG2E));
      }
    } else if (sel == 1) {
#pragma unroll
      for (int r = 0; r < 4; ++r) {
        int s = rowBase + rhalf + lh * 4 + r;
        int b = s >> 12, sl = s & 4095;
        int ch = sl >> 7, rl = sl & 127;
        int byte = (rl * 128 + c64 * 2) ^ ((rl & 7) << 4);
        *(unsigned short*)((char*)kswz + (((size_t)(b * 32 + ch)) << 14) + byte) =
            f2bf(acc[cf][r] + bb);
      }
    } else {
      ushort4v w;
#pragma unroll
      for (int r = 0; r < 4; ++r) w[r] = f2bf(acc[cf][r] + bb);
      int s0 = rowBase + rhalf + lh * 4;
      int b = s0 >> 12, sl0 = s0 & 4095;
      int ch = sl0 >> 7, r0 = sl0 & 127;
      int byte = (c64 * 256 + r0 * 2) ^ ((c64 & 7) << 4);
      *(ushort4v*)((char*)vswz + (((size_t)(b * 32 + ch)) << 14) + byte) = w;
    }
  }
}

// ---- causal flash attention v3: 4 waves, 64 q-rows/wave, kv-split 2 --------
// block = (batch, 64-row q-tile T, kv-half h). Each wave: all 64 q rows x
// 32-kv slice of each 128-chunk. Partials atomically merged into out + lacc.
__global__ __launch_bounds__(256, 2) void attn_kernel(
    const unsigned short* __restrict__ qb, const unsigned short* __restrict__ kswz,
    const unsigned short* __restrict__ vswz, float* __restrict__ out,
    float* __restrict__ lacc) {
  extern __shared__ __align__(16) char smem[];
  char* Kb = smem;                        // 16 KB K chunk (swizzled panel copy)
  char* Vb = smem + 16384;                // 16 KB V chunk
  char* Pall = smem + 32768;              // 4 x 4 KB per-wave P [64][32]
  float* obuf = (float*)(smem + 49152);   // 16 KB merge [64][64]
  float* lsumb = (float*)(smem + 65536);  // 256 B

  int tid = threadIdx.x, wave = tid >> 6, lane = tid & 63;
  int l15 = lane & 15, lh = lane >> 4;
  int bid = blockIdx.x;
  int h = bid >> 8;                  // kv half (0: even chunks, 1: odd chunks)
  int j = bid & 255;
  int batch = j & 3;
  int Ts = j >> 2;                   // 0..63
  int T = h ? Ts : 63 - Ts;          // big-T first for h=0 (LPT-ish)
  int Tq = T * 64;
  int nch = (T >> 1) + 1;            // KV chunks of 128 covering [0, Tq+63]
  const size_t bO = (size_t)batch * 262144;

  for (int i = tid; i < 4096; i += 256) obuf[i] = 0.f;
  if (tid < 64) lsumb[tid] = 0.f;
  __syncthreads();

  // Q: all 64 rows of the tile in registers
  bf16x8 qf[4][2];
#pragma unroll
  for (int rf = 0; rf < 4; ++rf)
#pragma unroll
    for (int ks = 0; ks < 2; ++ks)
      qf[rf][ks] = ld_bf8_g(qb + bO + (size_t)(Tq + rf * 16 + l15) * 64 + ks * 32 + lh * 8);

  f32x4 zero4 = {0.f, 0.f, 0.f, 0.f};
  f32x4 o[4][4];
  float lsum[4][4];
#pragma unroll
  for (int rf = 0; rf < 4; ++rf) {
#pragma unroll
    for (int dcf = 0; dcf < 4; ++dcf) o[rf][dcf] = zero4;
#pragma unroll
    for (int r = 0; r < 4; ++r) lsum[rf][r] = 0.f;
  }

  const char* kpan = (const char*)kswz + ((size_t)batch << 19);
  const char* vpan = (const char*)vswz + ((size_t)batch << 19);
  char* P = Pall + wave * 4096;

  for (int c = h; c < nch; c += 2) {
    __syncthreads();              // previous chunk fully consumed
    {                             // stage K+V chunk (32 KB) via global_load_lds
      size_t co = ((size_t)c << 14) + wave * 1024 + lane * 16;
      int lo = wave * 1024;
#pragma unroll
      for (int r = 0; r < 4; ++r) {
        gload16(kpan + co + r * 4096, Kb + lo + r * 4096);
        gload16(vpan + co + r * 4096, Vb + lo + r * 4096);
      }
    }
    __syncthreads();              // drains vmcnt -> chunk visible

    // ---- QK^T: 64q x 32kv per wave ----
    f32x4 sc[4][2];
#pragma unroll
    for (int rf = 0; rf < 4; ++rf) { sc[rf][0] = zero4; sc[rf][1] = zero4; }
#pragma unroll
    for (int cf = 0; cf < 2; ++cf) {
      int kr = wave * 32 + cf * 16 + l15;
#pragma unroll
      for (int ks = 0; ks < 2; ++ks) {
        bf16x8 kf = ld_bf8_l(Kb + ((kr * 128 + ks * 64 + lh * 16) ^ ((kr & 7) << 4)));
#pragma unroll
        for (int rf = 0; rf < 4; ++rf)
          sc[rf][cf] = __builtin_amdgcn_mfma_f32_16x16x32_bf16(qf[rf][ks], kf, sc[rf][cf], 0, 0, 0);
      }
    }
    if (c == nch - 1) {  // only the last chunk crosses the diagonal
#pragma unroll
      for (int rf = 0; rf < 4; ++rf)
#pragma unroll
        for (int r = 0; r < 4; ++r) {
          int qg = Tq + rf * 16 + lh * 4 + r;
#pragma unroll
          for (int cf = 0; cf < 2; ++cf) {
            int kvg = c * 128 + wave * 32 + cf * 16 + l15;
            if (kvg > qg) sc[rf][cf][r] = -3.0e38f;
          }
        }
    }
    // ---- p = exp2(s - SHIFT); stage P [64][32] swz (row&12)<<2 ----
#pragma unroll
    for (int rf = 0; rf < 4; ++rf)
#pragma unroll
      for (int r = 0; r < 4; ++r) {
        int row = rf * 16 + lh * 4 + r;
#pragma unroll
        for (int cf = 0; cf < 2; ++cf) {
          float p = fast_exp2(sc[rf][cf][r] - SHIFT_L2);
          lsum[rf][r] += p;
          *(unsigned short*)(P + ((row * 64 + (cf * 16 + l15) * 2) ^ ((row & 12) << 2))) = f2bf(p);
        }
      }
    __builtin_amdgcn_wave_barrier();
    bf16x8 pf[4];
#pragma unroll
    for (int rf = 0; rf < 4; ++rf) {
      int row = rf * 16 + l15;
      pf[rf] = ld_bf8_l(P + ((row * 64 + lh * 16) ^ ((row & 12) << 2)));
    }
#pragma unroll
    for (int dcf = 0; dcf < 4; ++dcf) {
      int d = dcf * 16 + l15;
      bf16x8 vf = ld_bf8_l(Vb + ((d * 256 + wave * 64 + lh * 16) ^ ((d & 7) << 4)));
#pragma unroll
      for (int rf = 0; rf < 4; ++rf)
        o[rf][dcf] = __builtin_amdgcn_mfma_f32_16x16x32_bf16(pf[rf], vf, o[rf][dcf], 0, 0, 0);
    }
    __builtin_amdgcn_wave_barrier();
  }

  // ---- reduce lsum over the 16 column-lanes ----
#pragma unroll
  for (int rf = 0; rf < 4; ++rf)
#pragma unroll
    for (int r = 0; r < 4; ++r) {
      float v = lsum[rf][r];
      v += __shfl_xor(v, 1, 64);
      v += __shfl_xor(v, 2, 64);
      v += __shfl_xor(v, 4, 64);
      v += __shfl_xor(v, 8, 64);
      lsum[rf][r] = v;
    }

  // ---- merge 4 waves into obuf/lsumb, then atomically into out/lacc ----
  __syncthreads();
#pragma unroll
  for (int rf = 0; rf < 4; ++rf)
#pragma unroll
    for (int r = 0; r < 4; ++r) {
      int row = rf * 16 + lh * 4 + r;
      if (l15 == 0) atomicAdd(&lsumb[row], lsum[rf][r]);
#pragma unroll
      for (int dcf = 0; dcf < 4; ++dcf)
        atomicAdd(&obuf[row * 64 + dcf * 16 + l15], o[rf][dcf][r]);
    }
  __syncthreads();
#pragma unroll
  for (int v = 0; v < 16; ++v) {
    int i = tid * 16 + v;
    atomicAdd(&out[bO + (size_t)Tq * 64 + i], obuf[i]);
  }
  if (tid < 64) atomicAdd(&lacc[batch * 4096 + Tq + tid], lsumb[tid]);
}

// ---- final normalize: out /= lacc (in place) -------------------------------
__global__ __launch_bounds__(256) void norm_kernel(float* __restrict__ out,
                                                   const float* __restrict__ lacc) {
  int i = blockIdx.x * 256 + threadIdx.x;   // float4 index, 0..262143
  float4v v = ((float4v*)out)[i];
  float inv = 1.0f / lacc[i >> 4];
  v *= inv;
  ((float4v*)out)[i] = v;
}

extern "C" void kernel_launch(void* const* d_in, const int* in_sizes, int n_in,
                              void* d_out, int out_size, void* d_ws, size_t ws_size,
                              hipStream_t stream) {
  const float* x  = (const float*)d_in[0];
  const float* wq = (const float*)d_in[1];
  const float* bq = (const float*)d_in[2];
  const float* wk = (const float*)d_in[3];
  const float* bk = (const float*)d_in[4];
  const float* wv = (const float*)d_in[5];
  const float* bv = (const float*)d_in[6];

  unsigned short* Wt   = (unsigned short*)d_ws;     // 192*1024
  unsigned short* qbuf = Wt + 192 * 1024;           // [b*4096+s][64]
  unsigned short* kswz = qbuf + 16384 * 64;         // 4 x 32 x 16KB panels
  unsigned short* vswz = kswz + 16384 * 64;         // 4 x 32 x 16KB panels
  float*          lacc = (float*)(vswz + 16384 * 64);  // [4][4096]
  float*          outf = (float*)d_out;

  wprep_kernel<<<768, 256, 0, stream>>>(wq, wk, wv, Wt, outf, lacc);
  proj_kernel<<<512, 256, 0, stream>>>(x, Wt, bq, bk, bv, qbuf, kswz, vswz);
  attn_kernel<<<512, 256, 65792, stream>>>(qbuf, kswz, vswz, outf, lacc);
  norm_kernel<<<1024, 256, 0, stream>>>(outf, lacc);
}

// Round 8
// 89.129 us; speedup vs baseline: 1.8244x; 1.8244x over previous
//
#include <hip/hip_runtime.h>
#include <hip/hip_bf16.h>

using f32x4    = __attribute__((ext_vector_type(4))) float;
using bf16x8   = __attribute__((ext_vector_type(8))) __bf16;
using ushort8  = __attribute__((ext_vector_type(8))) unsigned short;
using ushort4v = __attribute__((ext_vector_type(4))) unsigned short;
using float4v  = __attribute__((ext_vector_type(4))) float;

#define LOG2E 1.44269504088896340736f
#define SHIFT_L2 5.77078016355585f   // 4 * log2(e): p = exp(s_true - 4)

static __device__ __forceinline__ unsigned short f2bf(float f) {
  union { __hip_bfloat16 h; unsigned short u; } cv;
  cv.h = __float2bfloat16(f);
  return cv.u;
}
static __device__ __forceinline__ bf16x8 ld_bf8_g(const unsigned short* p) {
  ushort8 u = *(const ushort8*)p;
  return __builtin_bit_cast(bf16x8, u);
}
static __device__ __forceinline__ bf16x8 ld_bf8_l(const char* p) {
  ushort8 u = *(const ushort8*)p;
  return __builtin_bit_cast(bf16x8, u);
}
static __device__ __forceinline__ float fast_exp2(float x) {
#if __has_builtin(__builtin_amdgcn_exp2f)
  return __builtin_amdgcn_exp2f(x);
#else
  return exp2f(x);
#endif
}
static __device__ __forceinline__ void gload16(const void* g, void* l) {
  __builtin_amdgcn_global_load_lds(
      (const __attribute__((address_space(1))) void*)g,
      (__attribute__((address_space(3))) void*)l, 16, 0, 0);
}

// ---------------- W prep: Wt[col(0..191)][k(0..1023)] bf16 -------------------
__global__ __launch_bounds__(256) void wprep_kernel(
    const float* __restrict__ wq, const float* __restrict__ wk,
    const float* __restrict__ wv, unsigned short* __restrict__ Wt) {
  int idx = blockIdx.x * 256 + threadIdx.x;   // 0 .. 196607
  int col = idx >> 10;                        // 0..191
  int k   = idx & 1023;
  const float* w = (col < 64) ? wq : (col < 128) ? wk : wv;
  int c = col & 63;
  Wt[idx] = f2bf(w[k * 64 + c]);
}

// -------- QKV projection: BM=32 (512 blocks), BN=192, BK=64 -----------------
// q scaled by 1/8*log2(e), layout [b*4096+s][64].
// k,v written into PRE-SWIZZLED 16 KB panels per (batch, 128-row chunk):
//   K panel byte = (r*128 + c*2)  ^ ((r&7)<<4)   (r = s&127, c = 0..63)
//   V panel byte = (d*256 + sl*2) ^ ((d&7)<<4)   (transposed; sl = s&127)
__global__ __launch_bounds__(256) void proj_kernel(
    const float* __restrict__ x, const unsigned short* __restrict__ Wt,
    const float* __restrict__ bq, const float* __restrict__ bk,
    const float* __restrict__ bv,
    unsigned short* __restrict__ qb, unsigned short* __restrict__ kswz,
    unsigned short* __restrict__ vswz) {
  __shared__ __align__(16) char As[32 * 128];
  __shared__ __align__(16) char Bs[192 * 128];
  int tid = threadIdx.x, wave = tid >> 6, lane = tid & 63;
  int rowBase = blockIdx.x * 32;
  int rhalf = (wave & 1) * 16;
  int chalf = (wave >> 1) * 96;
  int l15 = lane & 15, lh = lane >> 4;

  f32x4 zero4 = {0.f, 0.f, 0.f, 0.f};
  f32x4 acc[6];
#pragma unroll
  for (int i = 0; i < 6; ++i) acc[i] = zero4;

  for (int kt = 0; kt < 16; ++kt) {
    int k0 = kt * 64;
    {
      int row = tid >> 3, c0 = (tid & 7) * 8;
      const float4v* src = (const float4v*)(x + (size_t)(rowBase + row) * 1024 + k0 + c0);
      float4v f0 = src[0], f1 = src[1];
      ushort8 u;
#pragma unroll
      for (int e = 0; e < 4; ++e) { u[e] = f2bf(f0[e]); u[4 + e] = f2bf(f1[e]); }
      *(ushort8*)(As + ((row * 128 + c0 * 2) ^ ((row & 7) << 4))) = u;
    }
#pragma unroll
    for (int i = 0; i < 6; ++i) {
      int c = tid + 256 * i;
      int col = c >> 3, kc = c & 7;
      ushort8 v = *(const ushort8*)(Wt + (size_t)col * 1024 + k0 + kc * 8);
      *(ushort8*)(Bs + ((col * 128 + kc * 16) ^ ((col & 7) << 4))) = v;
    }
    __syncthreads();
    bf16x8 a[2];
#pragma unroll
    for (int ks = 0; ks < 2; ++ks) {
      int row = rhalf + l15;
      a[ks] = ld_bf8_l(As + ((row * 128 + ks * 64 + lh * 16) ^ ((row & 7) << 4)));
    }
#pragma unroll
    for (int cf = 0; cf < 6; ++cf) {
      int col = chalf + cf * 16 + l15;
#pragma unroll
      for (int ks = 0; ks < 2; ++ks) {
        bf16x8 b = ld_bf8_l(Bs + ((col * 128 + ks * 64 + lh * 16) ^ ((col & 7) << 4)));
        acc[cf] = __builtin_amdgcn_mfma_f32_16x16x32_bf16(a[ks], b, acc[cf], 0, 0, 0);
      }
    }
    __syncthreads();
  }
#pragma unroll
  for (int cf = 0; cf < 6; ++cf) {
    int col = chalf + cf * 16 + l15;
    int sel = col >> 6, c64 = col & 63;
    const float* bias = (sel == 0) ? bq : (sel == 1) ? bk : bv;
    float bb = bias[c64];
    if (sel == 0) {
#pragma unroll
      for (int r = 0; r < 4; ++r) {
        int row = rowBase + rhalf + lh * 4 + r;
        qb[(size_t)row * 64 + c64] = f2bf((acc[cf][r] + bb) * (0.125f * LOG2E));
      }
    } else if (sel == 1) {
#pragma unroll
      for (int r = 0; r < 4; ++r) {
        int s = rowBase + rhalf + lh * 4 + r;
        int b = s >> 12, sl = s & 4095;
        int ch = sl >> 7, rl = sl & 127;
        int byte = (rl * 128 + c64 * 2) ^ ((rl & 7) << 4);
        *(unsigned short*)((char*)kswz + (((size_t)(b * 32 + ch)) << 14) + byte) =
            f2bf(acc[cf][r] + bb);
      }
    } else {
      ushort4v w;
#pragma unroll
      for (int r = 0; r < 4; ++r) w[r] = f2bf(acc[cf][r] + bb);
      int s0 = rowBase + rhalf + lh * 4;
      int b = s0 >> 12, sl0 = s0 & 4095;
      int ch = sl0 >> 7, r0 = sl0 & 127;
      int byte = (c64 * 256 + r0 * 2) ^ ((c64 & 7) << 4);
      *(ushort4v*)((char*)vswz + (((size_t)(b * 32 + ch)) << 14) + byte) = w;
    }
  }
}

// ---- causal flash attention v4: balanced tile-pairs, 8 waves, 2 blocks/CU --
// grid 256 = 4 batch x 64 pairs. Block processes 32-row q-tiles {127-p, p}
// sequentially => every block runs 33-34 KV chunks (perfect LPT balance).
// Per chunk: stage K/V 32 KB (swizzled panels, global_load_lds), 8 waves =
// (2 q-halves x 4 kv-quarters), fixed-shift softmax, LDS-atomic merge.
__global__ __launch_bounds__(512, 4) void attn_kernel(
    const unsigned short* __restrict__ qb, const unsigned short* __restrict__ kswz,
    const unsigned short* __restrict__ vswz, float* __restrict__ out) {
  extern __shared__ __align__(16) char smem[];
  char* Kb = smem;                        // 16 KB K chunk
  char* Vb = smem + 16384;                // 16 KB V chunk
  char* Pall = smem + 32768;              // 8 x 2 KB per-wave P [16][128B]
  float* obuf = (float*)(smem + 49152);   // 8 KB merge [32][64]
  float* lsumb = (float*)(smem + 57344);  // 128 B

  int tid = threadIdx.x, wave = tid >> 6, lane = tid & 63;
  int l15 = lane & 15, lh = lane >> 4;
  int bid = blockIdx.x;
  int batch = bid & 3;                 // 2 XCDs per batch -> panels L2-resident
  int p = bid >> 2;                    // pair index 0..63
  int qh = wave >> 2;                  // q half (16 rows)
  int kvq = wave & 3;                  // kv quarter (32 kv)
  const size_t bO = (size_t)batch * 262144;
  const char* kpan = (const char*)kswz + ((size_t)batch << 19);
  const char* vpan = (const char*)vswz + ((size_t)batch << 19);
  char* P = Pall + wave * 2048;
  f32x4 zero4 = {0.f, 0.f, 0.f, 0.f};

#pragma unroll 1
  for (int ti = 0; ti < 2; ++ti) {
    int T = ti ? p : 127 - p;          // heavy tile first
    int Tq = T * 32;
    int nch = (T + 4) >> 2;            // chunks of 128 kv covering [0, Tq+31]

    __syncthreads();
    for (int i = tid; i < 2048; i += 512) obuf[i] = 0.f;
    if (tid < 32) lsumb[tid] = 0.f;

    bf16x8 qf[2];
#pragma unroll
    for (int ks = 0; ks < 2; ++ks)
      qf[ks] = ld_bf8_g(qb + bO + (size_t)(Tq + qh * 16 + l15) * 64 + ks * 32 + lh * 8);

    f32x4 o[4];
    float lsum[4];
#pragma unroll
    for (int i = 0; i < 4; ++i) { o[i] = zero4; lsum[i] = 0.f; }

#pragma unroll 1
    for (int c = 0; c < nch; ++c) {
      __syncthreads();               // prev chunk fully consumed (also covers obuf init)
      {                              // stage 32 KB: 4 KB per wave
        size_t co = ((size_t)c << 14) + wave * 2048 + lane * 16;
        gload16(kpan + co, Kb + wave * 2048);
        gload16(kpan + co + 1024, Kb + wave * 2048 + 1024);
        gload16(vpan + co, Vb + wave * 2048);
        gload16(vpan + co + 1024, Vb + wave * 2048 + 1024);
      }
      __syncthreads();               // vmcnt drain -> chunk visible

      // ---- QK^T: 16q x 32kv ----
      f32x4 sc[2];
      sc[0] = zero4; sc[1] = zero4;
#pragma unroll
      for (int cf = 0; cf < 2; ++cf) {
        int kr = kvq * 32 + cf * 16 + l15;
#pragma unroll
        for (int ks = 0; ks < 2; ++ks) {
          bf16x8 kf = ld_bf8_l(Kb + ((kr * 128 + ks * 64 + lh * 16) ^ ((kr & 7) << 4)));
          sc[cf] = __builtin_amdgcn_mfma_f32_16x16x32_bf16(qf[ks], kf, sc[cf], 0, 0, 0);
        }
      }
      if (c == nch - 1) {            // only the last chunk crosses the diagonal
#pragma unroll
        for (int r = 0; r < 4; ++r) {
          int qg = Tq + qh * 16 + lh * 4 + r;
#pragma unroll
          for (int cf = 0; cf < 2; ++cf) {
            int kvg = c * 128 + kvq * 32 + cf * 16 + l15;
            if (kvg > qg) sc[cf][r] = -3.0e38f;
          }
        }
      }
      // ---- p = exp2(s - SHIFT); stage P [16 rows][128B] swz (row&7)<<4 ----
#pragma unroll
      for (int r = 0; r < 4; ++r) {
        int row = lh * 4 + r;
#pragma unroll
        for (int cf = 0; cf < 2; ++cf) {
          float pv = fast_exp2(sc[cf][r] - SHIFT_L2);
          lsum[r] += pv;
          *(unsigned short*)(P + row * 128 + (((cf * 16 + l15) * 2) ^ ((row & 7) << 4))) = f2bf(pv);
        }
      }
      __builtin_amdgcn_wave_barrier();
      bf16x8 pf = ld_bf8_l(P + l15 * 128 + ((lh * 16) ^ ((l15 & 7) << 4)));
#pragma unroll
      for (int dcf = 0; dcf < 4; ++dcf) {
        int d = dcf * 16 + l15;
        bf16x8 vf = ld_bf8_l(Vb + ((d * 256 + kvq * 64 + lh * 16) ^ ((d & 7) << 4)));
        o[dcf] = __builtin_amdgcn_mfma_f32_16x16x32_bf16(pf, vf, o[dcf], 0, 0, 0);
      }
      __builtin_amdgcn_wave_barrier();
    }

    // ---- reduce lsum over the 16 column-lanes ----
#pragma unroll
    for (int r = 0; r < 4; ++r) {
      float v = lsum[r];
      v += __shfl_xor(v, 1, 64);
      v += __shfl_xor(v, 2, 64);
      v += __shfl_xor(v, 4, 64);
      v += __shfl_xor(v, 8, 64);
      lsum[r] = v;
    }

    // ---- merge 8 waves (4 kv-waves per q-half) via LDS atomics ----
    __syncthreads();
#pragma unroll
    for (int r = 0; r < 4; ++r) {
      int row = qh * 16 + lh * 4 + r;
      if (l15 == 0) atomicAdd(&lsumb[row], lsum[r]);
#pragma unroll
      for (int dcf = 0; dcf < 4; ++dcf)
        atomicAdd(&obuf[row * 64 + dcf * 16 + l15], o[dcf][r]);
    }
    __syncthreads();
    {
      int row = tid >> 4, d0 = (tid & 15) * 4;
      float inv = 1.0f / lsumb[row];
      float4v vv = *(float4v*)&obuf[row * 64 + d0];
      vv *= inv;
      *(float4v*)(out + bO + (size_t)(Tq + row) * 64 + d0) = vv;
    }
  }
}

extern "C" void kernel_launch(void* const* d_in, const int* in_sizes, int n_in,
                              void* d_out, int out_size, void* d_ws, size_t ws_size,
                              hipStream_t stream) {
  const float* x  = (const float*)d_in[0];
  const float* wq = (const float*)d_in[1];
  const float* bq = (const float*)d_in[2];
  const float* wk = (const float*)d_in[3];
  const float* bk = (const float*)d_in[4];
  const float* wv = (const float*)d_in[5];
  const float* bv = (const float*)d_in[6];

  unsigned short* Wt   = (unsigned short*)d_ws;     // 192*1024
  unsigned short* qbuf = Wt + 192 * 1024;           // [b*4096+s][64]
  unsigned short* kswz = qbuf + 16384 * 64;         // 4 x 32 x 16KB panels
  unsigned short* vswz = kswz + 16384 * 64;         // 4 x 32 x 16KB panels

  wprep_kernel<<<768, 256, 0, stream>>>(wq, wk, wv, Wt);
  proj_kernel<<<512, 256, 0, stream>>>(x, Wt, bq, bk, bv, qbuf, kswz, vswz);
  attn_kernel<<<256, 512, 57472, stream>>>(qbuf, kswz, vswz, (float*)d_out);
}

// Round 9
// 83.104 us; speedup vs baseline: 1.9567x; 1.0725x over previous
//
#include <hip/hip_runtime.h>
#include <hip/hip_bf16.h>

using f32x4    = __attribute__((ext_vector_type(4))) float;
using bf16x8   = __attribute__((ext_vector_type(8))) __bf16;
using ushort8  = __attribute__((ext_vector_type(8))) unsigned short;
using ushort4v = __attribute__((ext_vector_type(4))) unsigned short;
using float4v  = __attribute__((ext_vector_type(4))) float;

#define LOG2E 1.44269504088896340736f
#define SHIFT_L2 5.77078016355585f   // 4 * log2(e): p = exp(s_true - 4)

static __device__ __forceinline__ unsigned short f2bf(float f) {
  union { __hip_bfloat16 h; unsigned short u; } cv;
  cv.h = __float2bfloat16(f);
  return cv.u;
}
static __device__ __forceinline__ bf16x8 ld_bf8_g(const unsigned short* p) {
  ushort8 u = *(const ushort8*)p;
  return __builtin_bit_cast(bf16x8, u);
}
static __device__ __forceinline__ bf16x8 ld_bf8_l(const char* p) {
  ushort8 u = *(const ushort8*)p;
  return __builtin_bit_cast(bf16x8, u);
}
static __device__ __forceinline__ float fast_exp2(float x) {
#if __has_builtin(__builtin_amdgcn_exp2f)
  return __builtin_amdgcn_exp2f(x);
#else
  return exp2f(x);
#endif
}
static __device__ __forceinline__ void gload16(const void* g, void* l) {
  __builtin_amdgcn_global_load_lds(
      (const __attribute__((address_space(1))) void*)g,
      (__attribute__((address_space(3))) void*)l, 16, 0, 0);
}

// ---------------- W prep: Wt[col(0..191)][k(0..1023)] bf16 -------------------
__global__ __launch_bounds__(256) void wprep_kernel(
    const float* __restrict__ wq, const float* __restrict__ wk,
    const float* __restrict__ wv, unsigned short* __restrict__ Wt) {
  int idx = blockIdx.x * 256 + threadIdx.x;   // 0 .. 196607
  int col = idx >> 10;                        // 0..191
  int k   = idx & 1023;
  const float* w = (col < 64) ? wq : (col < 128) ? wk : wv;
  int c = col & 63;
  Wt[idx] = f2bf(w[k * 64 + c]);
}

// -------- QKV projection: BM=32 (512 blocks), BN=192, BK=64 -----------------
// q scaled by 1/8*log2(e), layout [b*4096+s][64].
// k,v written into PRE-SWIZZLED 16 KB panels per (batch, 128-row chunk):
//   K panel byte = (r*128 + c*2)  ^ ((r&7)<<4)   (r = s&127, c = 0..63)
//   V panel byte = (d*256 + sl*2) ^ ((d&7)<<4)   (transposed; sl = s&127)
__global__ __launch_bounds__(256) void proj_kernel(
    const float* __restrict__ x, const unsigned short* __restrict__ Wt,
    const float* __restrict__ bq, const float* __restrict__ bk,
    const float* __restrict__ bv,
    unsigned short* __restrict__ qb, unsigned short* __restrict__ kswz,
    unsigned short* __restrict__ vswz) {
  __shared__ __align__(16) char As[32 * 128];
  __shared__ __align__(16) char Bs[192 * 128];
  int tid = threadIdx.x, wave = tid >> 6, lane = tid & 63;
  int rowBase = blockIdx.x * 32;
  int rhalf = (wave & 1) * 16;
  int chalf = (wave >> 1) * 96;
  int l15 = lane & 15, lh = lane >> 4;

  f32x4 zero4 = {0.f, 0.f, 0.f, 0.f};
  f32x4 acc[6];
#pragma unroll
  for (int i = 0; i < 6; ++i) acc[i] = zero4;

  for (int kt = 0; kt < 16; ++kt) {
    int k0 = kt * 64;
    {
      int row = tid >> 3, c0 = (tid & 7) * 8;
      const float4v* src = (const float4v*)(x + (size_t)(rowBase + row) * 1024 + k0 + c0);
      float4v f0 = src[0], f1 = src[1];
      ushort8 u;
#pragma unroll
      for (int e = 0; e < 4; ++e) { u[e] = f2bf(f0[e]); u[4 + e] = f2bf(f1[e]); }
      *(ushort8*)(As + ((row * 128 + c0 * 2) ^ ((row & 7) << 4))) = u;
    }
#pragma unroll
    for (int i = 0; i < 6; ++i) {
      int c = tid + 256 * i;
      int col = c >> 3, kc = c & 7;
      ushort8 v = *(const ushort8*)(Wt + (size_t)col * 1024 + k0 + kc * 8);
      *(ushort8*)(Bs + ((col * 128 + kc * 16) ^ ((col & 7) << 4))) = v;
    }
    __syncthreads();
    bf16x8 a[2];
#pragma unroll
    for (int ks = 0; ks < 2; ++ks) {
      int row = rhalf + l15;
      a[ks] = ld_bf8_l(As + ((row * 128 + ks * 64 + lh * 16) ^ ((row & 7) << 4)));
    }
#pragma unroll
    for (int cf = 0; cf < 6; ++cf) {
      int col = chalf + cf * 16 + l15;
#pragma unroll
      for (int ks = 0; ks < 2; ++ks) {
        bf16x8 b = ld_bf8_l(Bs + ((col * 128 + ks * 64 + lh * 16) ^ ((col & 7) << 4)));
        acc[cf] = __builtin_amdgcn_mfma_f32_16x16x32_bf16(a[ks], b, acc[cf], 0, 0, 0);
      }
    }
    __syncthreads();
  }
#pragma unroll
  for (int cf = 0; cf < 6; ++cf) {
    int col = chalf + cf * 16 + l15;
    int sel = col >> 6, c64 = col & 63;
    const float* bias = (sel == 0) ? bq : (sel == 1) ? bk : bv;
    float bb = bias[c64];
    if (sel == 0) {
#pragma unroll
      for (int r = 0; r < 4; ++r) {
        int row = rowBase + rhalf + lh * 4 + r;
        qb[(size_t)row * 64 + c64] = f2bf((acc[cf][r] + bb) * (0.125f * LOG2E));
      }
    } else if (sel == 1) {
#pragma unroll
      for (int r = 0; r < 4; ++r) {
        int s = rowBase + rhalf + lh * 4 + r;
        int b = s >> 12, sl = s & 4095;
        int ch = sl >> 7, rl = sl & 127;
        int byte = (rl * 128 + c64 * 2) ^ ((rl & 7) << 4);
        *(unsigned short*)((char*)kswz + (((size_t)(b * 32 + ch)) << 14) + byte) =
            f2bf(acc[cf][r] + bb);
      }
    } else {
      ushort4v w;
#pragma unroll
      for (int r = 0; r < 4; ++r) w[r] = f2bf(acc[cf][r] + bb);
      int s0 = rowBase + rhalf + lh * 4;
      int b = s0 >> 12, sl0 = s0 & 4095;
      int ch = sl0 >> 7, r0 = sl0 & 127;
      int byte = (c64 * 256 + r0 * 2) ^ ((c64 & 7) << 4);
      *(ushort4v*)((char*)vswz + (((size_t)(b * 32 + ch)) << 14) + byte) = w;
    }
  }
}

// ---- causal flash attention v5: co-resident balanced pairs, 2+ blocks/CU ---
// grid 512 = 2 halves x (4 batch x 64 pairs). Block bid handles ONE 32-row
// q-tile: T = (bid>>8) ? p : 127-p, so blocks bid and bid+256 (same CU under
// round-robin dispatch) carry a heavy+light pair -> balanced per-CU work AND
// independent phases that overlap (one block's stage drain hides under the
// other block's compute). LDS 48.1 KB (obuf aliases the dead P region).
__global__ __launch_bounds__(512, 4) void attn_kernel(
    const unsigned short* __restrict__ qb, const unsigned short* __restrict__ kswz,
    const unsigned short* __restrict__ vswz, float* __restrict__ out) {
  extern __shared__ __align__(16) char smem[];
  char* Kb = smem;                        // 16 KB K chunk
  char* Vb = smem + 16384;                // 16 KB V chunk
  char* Pall = smem + 32768;              // 8 x 2 KB per-wave P [16][128B]
  float* obuf = (float*)(smem + 32768);   // ALIAS: merge [32][64] after loop
  float* lsumb = (float*)(smem + 49152);  // 128 B

  int tid = threadIdx.x, wave = tid >> 6, lane = tid & 63;
  int l15 = lane & 15, lh = lane >> 4;
  int bid = blockIdx.x;
  int ti = bid >> 8;                   // pair half
  int j = bid & 255;
  int batch = j & 3;
  int p = j >> 2;                      // pair index 0..63
  int T = ti ? p : 127 - p;            // heavy half first
  int Tq = T * 32;
  int nch = (T + 4) >> 2;              // chunks of 128 kv covering [0, Tq+31]
  int qh = wave >> 2;                  // q half (16 rows)
  int kvq = wave & 3;                  // kv quarter (32 kv)
  const size_t bO = (size_t)batch * 262144;
  const char* kpan = (const char*)kswz + ((size_t)batch << 19);
  const char* vpan = (const char*)vswz + ((size_t)batch << 19);
  char* P = Pall + wave * 2048;
  f32x4 zero4 = {0.f, 0.f, 0.f, 0.f};

  bf16x8 qf[2];
#pragma unroll
  for (int ks = 0; ks < 2; ++ks)
    qf[ks] = ld_bf8_g(qb + bO + (size_t)(Tq + qh * 16 + l15) * 64 + ks * 32 + lh * 8);

  f32x4 o[4];
  float lsum[4];
#pragma unroll
  for (int i = 0; i < 4; ++i) { o[i] = zero4; lsum[i] = 0.f; }

#pragma unroll 1
  for (int c = 0; c < nch; ++c) {
    __syncthreads();               // prev chunk fully consumed
    {                              // stage 32 KB: 4 KB per wave
      size_t co = ((size_t)c << 14) + wave * 2048 + lane * 16;
      gload16(kpan + co, Kb + wave * 2048);
      gload16(kpan + co + 1024, Kb + wave * 2048 + 1024);
      gload16(vpan + co, Vb + wave * 2048);
      gload16(vpan + co + 1024, Vb + wave * 2048 + 1024);
    }
    __syncthreads();               // vmcnt drain -> chunk visible

    // ---- QK^T: 16q x 32kv ----
    f32x4 sc[2];
    sc[0] = zero4; sc[1] = zero4;
#pragma unroll
    for (int cf = 0; cf < 2; ++cf) {
      int kr = kvq * 32 + cf * 16 + l15;
#pragma unroll
      for (int ks = 0; ks < 2; ++ks) {
        bf16x8 kf = ld_bf8_l(Kb + ((kr * 128 + ks * 64 + lh * 16) ^ ((kr & 7) << 4)));
        sc[cf] = __builtin_amdgcn_mfma_f32_16x16x32_bf16(qf[ks], kf, sc[cf], 0, 0, 0);
      }
    }
    if (c == nch - 1) {            // only the last chunk crosses the diagonal
#pragma unroll
      for (int r = 0; r < 4; ++r) {
        int qg = Tq + qh * 16 + lh * 4 + r;
#pragma unroll
        for (int cf = 0; cf < 2; ++cf) {
          int kvg = c * 128 + kvq * 32 + cf * 16 + l15;
          if (kvg > qg) sc[cf][r] = -3.0e38f;
        }
      }
    }
    // ---- p = exp2(s - SHIFT); stage P [16 rows][128B] swz (row&7)<<4 ----
#pragma unroll
    for (int r = 0; r < 4; ++r) {
      int row = lh * 4 + r;
#pragma unroll
      for (int cf = 0; cf < 2; ++cf) {
        float pv = fast_exp2(sc[cf][r] - SHIFT_L2);
        lsum[r] += pv;
        *(unsigned short*)(P + row * 128 + (((cf * 16 + l15) * 2) ^ ((row & 7) << 4))) = f2bf(pv);
      }
    }
    __builtin_amdgcn_wave_barrier();
    bf16x8 pf = ld_bf8_l(P + l15 * 128 + ((lh * 16) ^ ((l15 & 7) << 4)));
#pragma unroll
    for (int dcf = 0; dcf < 4; ++dcf) {
      int d = dcf * 16 + l15;
      bf16x8 vf = ld_bf8_l(Vb + ((d * 256 + kvq * 64 + lh * 16) ^ ((d & 7) << 4)));
      o[dcf] = __builtin_amdgcn_mfma_f32_16x16x32_bf16(pf, vf, o[dcf], 0, 0, 0);
    }
    __builtin_amdgcn_wave_barrier();
  }

  // ---- reduce lsum over the 16 column-lanes (register-only) ----
#pragma unroll
  for (int r = 0; r < 4; ++r) {
    float v = lsum[r];
    v += __shfl_xor(v, 1, 64);
    v += __shfl_xor(v, 2, 64);
    v += __shfl_xor(v, 4, 64);
    v += __shfl_xor(v, 8, 64);
    lsum[r] = v;
  }

  // ---- merge 8 waves (4 kv-waves per q-half) via LDS atomics ----
  __syncthreads();                 // all P reads done; safe to reuse as obuf
  for (int i = tid; i < 2048; i += 512) obuf[i] = 0.f;
  if (tid < 32) lsumb[tid] = 0.f;
  __syncthreads();
#pragma unroll
  for (int r = 0; r < 4; ++r) {
    int row = qh * 16 + lh * 4 + r;
    if (l15 == 0) atomicAdd(&lsumb[row], lsum[r]);
#pragma unroll
    for (int dcf = 0; dcf < 4; ++dcf)
      atomicAdd(&obuf[row * 64 + dcf * 16 + l15], o[dcf][r]);
  }
  __syncthreads();
  {
    int row = tid >> 4, d0 = (tid & 15) * 4;
    float inv = 1.0f / lsumb[row];
    float4v vv = *(float4v*)&obuf[row * 64 + d0];
    vv *= inv;
    *(float4v*)(out + bO + (size_t)(Tq + row) * 64 + d0) = vv;
  }
}

extern "C" void kernel_launch(void* const* d_in, const int* in_sizes, int n_in,
                              void* d_out, int out_size, void* d_ws, size_t ws_size,
                              hipStream_t stream) {
  const float* x  = (const float*)d_in[0];
  const float* wq = (const float*)d_in[1];
  const float* bq = (const float*)d_in[2];
  const float* wk = (const float*)d_in[3];
  const float* bk = (const float*)d_in[4];
  const float* wv = (const float*)d_in[5];
  const float* bv = (const float*)d_in[6];

  unsigned short* Wt   = (unsigned short*)d_ws;     // 192*1024
  unsigned short* qbuf = Wt + 192 * 1024;           // [b*4096+s][64]
  unsigned short* kswz = qbuf + 16384 * 64;         // 4 x 32 x 16KB panels
  unsigned short* vswz = kswz + 16384 * 64;         // 4 x 32 x 16KB panels

  wprep_kernel<<<768, 256, 0, stream>>>(wq, wk, wv, Wt);
  proj_kernel<<<512, 256, 0, stream>>>(x, Wt, bq, bk, bv, qbuf, kswz, vswz);
  attn_kernel<<<512, 512, 49280, stream>>>(qbuf, kswz, vswz, (float*)d_out);
}